// Round 1
// baseline (34663.873 us; speedup 1.0000x reference)
//
#include <hip/hip_runtime.h>
#include <cstddef>

#define NB 32
#define NT 512
#define ND 1024
#define NH 1024
#define NG 4096  // 4*NH

// ---------------------------------------------------------------------------
// Kernel 1: xw_chunk[(b*Tc + tt), n] = sum_k x[b, t0+tt, k] * Wx[k, n] + bias[n]
// fp32 tiled GEMM, BM=BN=64, BK=32, 256 threads, 4x4 microtile.
// ---------------------------------------------------------------------------
__global__ __launch_bounds__(256) void gemm_xw(
    const float* __restrict__ X,    // [NB, NT, ND]
    const float* __restrict__ Wx,   // [ND, NG]
    const float* __restrict__ bias, // [NG]
    float* __restrict__ XW,         // [NB*Tc, NG]
    int t0, int Tc)
{
    __shared__ float As[64][36];   // [m][k], pad to 36 (144B rows, 16B-aligned)
    __shared__ float Bs[32][68];   // [k][n], pad to 68 (272B rows, 16B-aligned)

    const int tid = threadIdx.x;
    const int tx  = tid & 15;        // n-dir, 4 cols each
    const int ty  = tid >> 4;        // m-dir, 4 rows each
    const int n0  = blockIdx.x * 64;
    const int m0  = blockIdx.y * 64;

    // A staging: each thread loads 2 float4 from one row
    const int ar  = tid >> 2;             // tile row 0..63
    const int akk = (tid & 3) * 8;        // k offset 0,8,16,24
    const int rm  = m0 + ar;              // chunk row
    const int bidx = rm / Tc;
    const int tt   = rm - bidx * Tc;
    const float* arow = X + ((size_t)bidx * NT + (t0 + tt)) * ND;

    // B staging: each thread loads 2 float4 from one row of Wx
    const int br  = tid >> 3;             // k row 0..31
    const int bnn = (tid & 7) * 8;        // n offset 0..56

    float acc[4][4] = {};

    for (int k0 = 0; k0 < ND; k0 += 32) {
        float4 a0 = *(const float4*)&arow[k0 + akk];
        float4 a1 = *(const float4*)&arow[k0 + akk + 4];
        float4 b0 = *(const float4*)&Wx[(size_t)(k0 + br) * NG + n0 + bnn];
        float4 b1 = *(const float4*)&Wx[(size_t)(k0 + br) * NG + n0 + bnn + 4];
        __syncthreads();   // previous tile's compute must finish before overwrite
        *(float4*)&As[ar][akk]     = a0;
        *(float4*)&As[ar][akk + 4] = a1;
        *(float4*)&Bs[br][bnn]     = b0;
        *(float4*)&Bs[br][bnn + 4] = b1;
        __syncthreads();
        #pragma unroll
        for (int k = 0; k < 32; ++k) {
            float4 bv = *(const float4*)&Bs[k][tx * 4];
            float a_[4];
            #pragma unroll
            for (int i = 0; i < 4; ++i) a_[i] = As[ty * 4 + i][k];
            #pragma unroll
            for (int i = 0; i < 4; ++i) {
                acc[i][0] += a_[i] * bv.x;
                acc[i][1] += a_[i] * bv.y;
                acc[i][2] += a_[i] * bv.z;
                acc[i][3] += a_[i] * bv.w;
            }
        }
    }

    #pragma unroll
    for (int i = 0; i < 4; ++i) {
        int r = m0 + ty * 4 + i;
        int n = n0 + tx * 4;
        float4 o;
        o.x = acc[i][0] + bias[n + 0];
        o.y = acc[i][1] + bias[n + 1];
        o.z = acc[i][2] + bias[n + 2];
        o.w = acc[i][3] + bias[n + 3];
        *(float4*)&XW[(size_t)r * NG + n] = o;
    }
}

// ---------------------------------------------------------------------------
// Kernel 2: one LSTM timestep.
// gates[b, n] = xw[b, t, n] + sum_k h_prev[b, k] * Wh[k, n]
// 256 blocks, each owns 4 h-columns (16 gate cols: seg*NH + j0..j0+3).
// 256 threads: (seg 0..3) x (b 0..31) x (kh 0..1 split-K halves).
// h_prev staged in LDS in 2x(32x128) tiles (one per K-half).
// ---------------------------------------------------------------------------
__global__ __launch_bounds__(256) void lstm_step(
    const float* __restrict__ XW,    // [NB*Tc, NG]
    const float* __restrict__ Wh,    // [NH, NG]
    const float* __restrict__ hprev, // row stride hstride
    size_t hstride,
    float* __restrict__ cstate,      // [NB, NH]  (== cT slot of d_out)
    float* __restrict__ out,         // [NB, NT, NH]
    float* __restrict__ hT,          // [NB, NH]
    int t, int trel, int Tc)
{
    __shared__ float hs2[2][32][132];  // pad 132: bank = (4b + k) % 32, conflict-free
    __shared__ float gsh[32][4][4];    // [b][gate][jj]

    const int tid = threadIdx.x;
    const int seg = tid & 3;
    const int b   = (tid >> 2) & 31;
    const int kh  = tid >> 7;           // K half: 0 -> k<512, 1 -> k>=512
    const int j0  = blockIdx.x * 4;
    const int n4  = seg * NH + j0;      // 16B-aligned gate column base

    float4 acc;
    if (kh == 0) {
        acc = *(const float4*)&XW[((size_t)(b * Tc + trel)) * NG + n4];
    } else {
        acc = make_float4(0.f, 0.f, 0.f, 0.f);
    }

    for (int tile = 0; tile < 4; ++tile) {
        __syncthreads();  // previous tile's reads done before overwrite
        #pragma unroll
        for (int u = 0; u < 8; ++u) {
            int f    = tid + u * 256;        // float4 index 0..2047
            int half = f >> 10;              // which K-half tile
            int fi   = f & 1023;
            int r    = fi >> 5;              // batch row 0..31
            int kk   = (fi & 31) * 4;        // 0..124
            int ksrc = half * 512 + tile * 128 + kk;
            *(float4*)&hs2[half][r][kk] =
                *(const float4*)&hprev[(size_t)r * hstride + ksrc];
        }
        __syncthreads();
        const int kg0 = kh * 512 + tile * 128;
        const float* hrow = &hs2[kh][b][0];
        #pragma unroll 8
        for (int kk = 0; kk < 128; ++kk) {
            float  hv = hrow[kk];
            float4 w  = *(const float4*)&Wh[(size_t)(kg0 + kk) * NG + n4];
            acc.x += hv * w.x;
            acc.y += hv * w.y;
            acc.z += hv * w.z;
            acc.w += hv * w.w;
        }
    }

    // reduce the two K halves into gsh
    if (kh == 1) *(float4*)&gsh[b][seg][0] = acc;
    __syncthreads();
    if (kh == 0) {
        float4 o = *(const float4*)&gsh[b][seg][0];
        o.x += acc.x; o.y += acc.y; o.z += acc.z; o.w += acc.w;
        *(float4*)&gsh[b][seg][0] = o;
    }
    __syncthreads();

    // elementwise LSTM update: 128 threads, one (b, j) each
    if (tid < 128) {
        const int bb = tid >> 2;
        const int jj = tid & 3;
        const int j  = j0 + jj;
        float gi = gsh[bb][0][jj];
        float gf = gsh[bb][1][jj];
        float gg = gsh[bb][2][jj];
        float go = gsh[bb][3][jj];

        float iv = 1.f / (1.f + __expf(-gi));
        float fv = 1.f / (1.f + __expf(-gf));
        float gv = tanhf(gg);
        float ov = 1.f / (1.f + __expf(-go));

        float cv = cstate[bb * NH + j];
        float cn = fv * cv + iv * gv;
        float hn = ov * tanhf(cn);

        cstate[bb * NH + j] = cn;
        out[((size_t)bb * NT + t) * NH + j] = hn;
        if (t == NT - 1) hT[bb * NH + j] = hn;
    }
}

// ---------------------------------------------------------------------------
extern "C" void kernel_launch(void* const* d_in, const int* in_sizes, int n_in,
                              void* d_out, int out_size, void* d_ws, size_t ws_size,
                              hipStream_t stream) {
    const float* x    = (const float*)d_in[0];
    const float* c0   = (const float*)d_in[1];
    const float* h0   = (const float*)d_in[2];
    const float* Wx   = (const float*)d_in[3];
    const float* Wh   = (const float*)d_in[4];
    const float* bias = (const float*)d_in[5];

    float* out = (float*)d_out;
    float* cT  = out + (size_t)NB * NT * NH;  // running c state lives here
    float* hT  = cT + (size_t)NB * NH;
    float* xw  = (float*)d_ws;

    // choose time-chunk size for the xW workspace
    int Tc = 512;
    while (Tc > 2 && (size_t)NB * Tc * NG * sizeof(float) > ws_size) Tc >>= 1;

    // c <- c0 (every call: harness poisons d_out before timing)
    hipMemcpyAsync(cT, c0, (size_t)NB * NH * sizeof(float),
                   hipMemcpyDeviceToDevice, stream);

    for (int t0 = 0; t0 < NT; t0 += Tc) {
        dim3 g(NG / 64, (NB * Tc) / 64);
        gemm_xw<<<g, 256, 0, stream>>>(x, Wx, bias, xw, t0, Tc);
        for (int t = t0; t < t0 + Tc; ++t) {
            const float* hp;
            size_t hstr;
            if (t == 0) { hp = h0;                        hstr = NH; }
            else        { hp = out + (size_t)(t - 1) * NH; hstr = (size_t)NT * NH; }
            lstm_step<<<256, 256, 0, stream>>>(xw, Wh, hp, hstr, cT, out, hT,
                                               t, t - t0, Tc);
        }
    }
}

// Round 2
// 7997.677 us; speedup vs baseline: 4.3342x; 4.3342x over previous
//
#include <hip/hip_runtime.h>
#include <cstddef>

#define NB 32
#define NT 512
#define ND 1024
#define NH 1024
#define NG 4096  // 4*NH

// ---------------------------------------------------------------------------
// Kernel 1: xw_chunk[(b*Tc + tt), n] = sum_k x[b, t0+tt, k] * Wx[k, n] + bias[n]
// fp32 tiled GEMM, BM=BN=64, BK=32, 256 threads, 4x4 microtile. (unchanged)
// ---------------------------------------------------------------------------
__global__ __launch_bounds__(256) void gemm_xw(
    const float* __restrict__ X,    // [NB, NT, ND]
    const float* __restrict__ Wx,   // [ND, NG]
    const float* __restrict__ bias, // [NG]
    float* __restrict__ XW,         // [NB*Tc, NG]
    int t0, int Tc)
{
    __shared__ float As[64][36];
    __shared__ float Bs[32][68];

    const int tid = threadIdx.x;
    const int tx  = tid & 15;
    const int ty  = tid >> 4;
    const int n0  = blockIdx.x * 64;
    const int m0  = blockIdx.y * 64;

    const int ar  = tid >> 2;
    const int akk = (tid & 3) * 8;
    const int rm  = m0 + ar;
    const int bidx = rm / Tc;
    const int tt   = rm - bidx * Tc;
    const float* arow = X + ((size_t)bidx * NT + (t0 + tt)) * ND;

    const int br  = tid >> 3;
    const int bnn = (tid & 7) * 8;

    float acc[4][4] = {};

    for (int k0 = 0; k0 < ND; k0 += 32) {
        float4 a0 = *(const float4*)&arow[k0 + akk];
        float4 a1 = *(const float4*)&arow[k0 + akk + 4];
        float4 b0 = *(const float4*)&Wx[(size_t)(k0 + br) * NG + n0 + bnn];
        float4 b1 = *(const float4*)&Wx[(size_t)(k0 + br) * NG + n0 + bnn + 4];
        __syncthreads();
        *(float4*)&As[ar][akk]     = a0;
        *(float4*)&As[ar][akk + 4] = a1;
        *(float4*)&Bs[br][bnn]     = b0;
        *(float4*)&Bs[br][bnn + 4] = b1;
        __syncthreads();
        #pragma unroll
        for (int k = 0; k < 32; ++k) {
            float4 bv = *(const float4*)&Bs[k][tx * 4];
            float a_[4];
            #pragma unroll
            for (int i = 0; i < 4; ++i) a_[i] = As[ty * 4 + i][k];
            #pragma unroll
            for (int i = 0; i < 4; ++i) {
                acc[i][0] += a_[i] * bv.x;
                acc[i][1] += a_[i] * bv.y;
                acc[i][2] += a_[i] * bv.z;
                acc[i][3] += a_[i] * bv.w;
            }
        }
    }

    #pragma unroll
    for (int i = 0; i < 4; ++i) {
        int r = m0 + ty * 4 + i;
        int n = n0 + tx * 4;
        float4 o;
        o.x = acc[i][0] + bias[n + 0];
        o.y = acc[i][1] + bias[n + 1];
        o.z = acc[i][2] + bias[n + 2];
        o.w = acc[i][3] + bias[n + 3];
        *(float4*)&XW[(size_t)r * NG + n] = o;
    }
}

// ---------------------------------------------------------------------------
// Kernel 2: pack Wh into per-block shards.
// whp[blk][k][c] where c = 4*g + jj  ->  Wh[k][g*NH + blk*4 + jj]
// ---------------------------------------------------------------------------
__global__ __launch_bounds__(256) void pack_wh(const float* __restrict__ Wh,
                                               float* __restrict__ whp)
{
    int idx = blockIdx.x * 256 + threadIdx.x;   // 1,048,576 total
    int blk = idx & 255;
    int g   = (idx >> 8) & 3;
    int k   = idx >> 10;
    float4 v = *(const float4*)&Wh[(size_t)k * NG + g * NH + blk * 4];
    *(float4*)&whp[((size_t)blk * 1024 + k) * 16 + g * 4] = v;
}

// ---------------------------------------------------------------------------
// Kernel 3: transpose h0 into hT[j][b]
// ---------------------------------------------------------------------------
__global__ __launch_bounds__(256) void transpose_h0(const float* __restrict__ h0,
                                                    float* __restrict__ hT)
{
    int idx = blockIdx.x * 256 + threadIdx.x;  // 32768 total
    int j = idx >> 5, b = idx & 31;
    hT[j * 32 + b] = h0[b * NH + j];
}

// ---------------------------------------------------------------------------
// Kernel 4: one LSTM timestep, register-tiled.
// Block blk owns h-cols [4*blk, 4*blk+4) => 16 gate cols c=4*g+jj.
// Thread (rg 0..3, cg 0..1, ks 0..31): 8 rows x 8 cols x 32 k outer-product.
// Operands stream global->reg: whp (L2-hot shard) + hT[k][b] (coalesced).
// Split-K reduced via shfl_xor fold + LDS.
// ---------------------------------------------------------------------------
__global__ __launch_bounds__(256, 1) void lstm_step2(
    const float* __restrict__ XW,     // [NB*Tc, NG]
    const float* __restrict__ whp,    // [256][1024][16]
    const float* __restrict__ hTprev, // [NH][NB]
    float* __restrict__ hTnext,       // [NH][NB]
    float* __restrict__ cstate,       // [NB, NH] (cT slot of d_out)
    float* __restrict__ out,          // [NB, NT, NH]
    float* __restrict__ hTout,        // [NB, NH]
    int t, int trel, int Tc)
{
    __shared__ float red[128 * 68];   // 34.8 KB: [q*16 + ks/2][68]
    __shared__ float gsh[32 * 17];

    const int tid = threadIdx.x;
    const int rg  = tid & 3;          // rows 8*rg .. 8*rg+7
    const int cg  = (tid >> 2) & 1;   // cols 8*cg .. 8*cg+7
    const int ks  = tid >> 3;         // k in [32*ks, 32*ks+32)
    const int blk = blockIdx.x;
    const int jc0 = blk * 4;

    const float* wrow = whp + ((size_t)blk * 1024 + ks * 32) * 16 + cg * 8;
    const float* hrow = hTprev + (size_t)(ks * 32) * 32 + rg * 8;

    float acc[8][8];
    #pragma unroll
    for (int r = 0; r < 8; ++r)
        #pragma unroll
        for (int c = 0; c < 8; ++c) acc[r][c] = 0.f;

    #pragma unroll 4
    for (int kk = 0; kk < 32; ++kk) {
        float4 ha = *(const float4*)&hrow[kk * 32];
        float4 hb = *(const float4*)&hrow[kk * 32 + 4];
        float4 wa = *(const float4*)&wrow[kk * 16];
        float4 wb = *(const float4*)&wrow[kk * 16 + 4];
        float hv[8] = {ha.x, ha.y, ha.z, ha.w, hb.x, hb.y, hb.z, hb.w};
        float wv[8] = {wa.x, wa.y, wa.z, wa.w, wb.x, wb.y, wb.z, wb.w};
        #pragma unroll
        for (int r = 0; r < 8; ++r)
            #pragma unroll
            for (int c = 0; c < 8; ++c)
                acc[r][c] += hv[r] * wv[c];
    }

    // fold ks-parity pairs (lanes tid and tid^8 differ only in ks LSB)
    #pragma unroll
    for (int r = 0; r < 8; ++r)
        #pragma unroll
        for (int c = 0; c < 8; ++c)
            acc[r][c] += __shfl_xor(acc[r][c], 8);

    const int q = cg * 4 + rg;
    if ((ks & 1) == 0) {
        float* myrow = &red[(q * 16 + (ks >> 1)) * 68];
        #pragma unroll
        for (int r = 0; r < 8; ++r) {
            *(float4*)&myrow[r * 8 + 0] =
                make_float4(acc[r][0], acc[r][1], acc[r][2], acc[r][3]);
            *(float4*)&myrow[r * 8 + 4] =
                make_float4(acc[r][4], acc[r][5], acc[r][6], acc[r][7]);
        }
    }
    __syncthreads();

    // reduce 16 k-partials per output; add xW; stash gates in gsh
    #pragma unroll
    for (int oo = 0; oo < 2; ++oo) {
        int oi = tid * 2 + oo;        // 0..511
        int b  = oi >> 4;             // 0..31
        int c  = oi & 15;             // 0..15
        int qq = (c >> 3) * 4 + (b >> 3);
        int e  = (b & 7) * 8 + (c & 7);
        float s = 0.f;
        #pragma unroll 8
        for (int kss = 0; kss < 16; ++kss)
            s += red[(qq * 16 + kss) * 68 + e];
        int n = (c >> 2) * NH + jc0 + (c & 3);
        s += XW[((size_t)b * Tc + trel) * NG + n];
        gsh[b * 17 + c] = s;
    }
    __syncthreads();

    // elementwise LSTM update: 128 threads, one (b, jj) each
    if (tid < 128) {
        const int b  = tid & 31;
        const int jj = tid >> 5;
        float gi = gsh[b * 17 + jj];
        float gf = gsh[b * 17 + 4 + jj];
        float gg = gsh[b * 17 + 8 + jj];
        float go = gsh[b * 17 + 12 + jj];

        float iv = 1.f / (1.f + __expf(-gi));
        float fv = 1.f / (1.f + __expf(-gf));
        float gv = tanhf(gg);
        float ov = 1.f / (1.f + __expf(-go));

        const int j = jc0 + jj;
        float cv = cstate[b * NH + j];
        float cn = fv * cv + iv * gv;
        float hn = ov * tanhf(cn);

        cstate[b * NH + j] = cn;
        out[((size_t)b * NT + t) * NH + j] = hn;
        hTnext[j * 32 + b] = hn;
        if (t == NT - 1) hTout[b * NH + j] = hn;
    }
}

// ---------------------------------------------------------------------------
extern "C" void kernel_launch(void* const* d_in, const int* in_sizes, int n_in,
                              void* d_out, int out_size, void* d_ws, size_t ws_size,
                              hipStream_t stream) {
    const float* x    = (const float*)d_in[0];
    const float* c0   = (const float*)d_in[1];
    const float* h0   = (const float*)d_in[2];
    const float* Wx   = (const float*)d_in[3];
    const float* Wh   = (const float*)d_in[4];
    const float* bias = (const float*)d_in[5];

    float* out = (float*)d_out;
    float* cT  = out + (size_t)NB * NT * NH;  // running c state lives here
    float* hT  = cT + (size_t)NB * NH;

    float* whp = (float*)d_ws;                         // 16 MB
    float* hT0 = whp + (size_t)256 * 1024 * 16;        // 128 KB
    float* hT1 = hT0 + 1024 * 32;                      // 128 KB
    float* xw  = hT1 + 1024 * 32;

    const size_t base_bytes = ((size_t)256 * 1024 * 16 + 2 * 1024 * 32) * sizeof(float);
    int Tc = 512;
    while (Tc > 2 && base_bytes + (size_t)NB * Tc * NG * sizeof(float) > ws_size)
        Tc >>= 1;

    pack_wh<<<4096, 256, 0, stream>>>(Wh, whp);
    transpose_h0<<<128, 256, 0, stream>>>(h0, hT0);
    hipMemcpyAsync(cT, c0, (size_t)NB * NH * sizeof(float),
                   hipMemcpyDeviceToDevice, stream);

    for (int t0 = 0; t0 < NT; t0 += Tc) {
        dim3 g(NG / 64, (NB * Tc) / 64);
        gemm_xw<<<g, 256, 0, stream>>>(x, Wx, bias, xw, t0, Tc);
        for (int t = t0; t < t0 + Tc; ++t) {
            const float* hp = (t & 1) ? hT1 : hT0;
            float*       hn = (t & 1) ? hT0 : hT1;
            lstm_step2<<<256, 256, 0, stream>>>(xw, whp, hp, hn, cT, out, hT,
                                                t, t - t0, Tc);
        }
    }
}

// Round 3
// 4601.199 us; speedup vs baseline: 7.5337x; 1.7382x over previous
//
#include <hip/hip_runtime.h>
#include <cstddef>

#define NB 32
#define NT 512
#define ND 1024
#define NH 1024
#define NG 4096  // 4*NH

typedef unsigned short ushortT;
typedef __attribute__((ext_vector_type(8))) short short8;   // 8 bf16 = 4 VGPR
typedef __attribute__((ext_vector_type(4))) float f32x4;

__device__ __forceinline__ ushortT f2bf(float f) {
    union { float f; unsigned u; } v; v.f = f;
    unsigned r = v.u + 0x7FFFu + ((v.u >> 16) & 1u);   // RNE
    return (ushortT)(r >> 16);
}

// ---------------------------------------------------------------------------
// cast float -> bf16, 4 elems/thread (n4 = total/4)
// ---------------------------------------------------------------------------
__global__ __launch_bounds__(256) void cast_bf16(const float* __restrict__ src,
                                                 ushortT* __restrict__ dst, int n4)
{
    int i = blockIdx.x * 256 + threadIdx.x;
    if (i < n4) {
        float4 v = ((const float4*)src)[i];
        ushort4 o;
        o.x = f2bf(v.x); o.y = f2bf(v.y); o.z = f2bf(v.z); o.w = f2bf(v.w);
        ((ushort4*)dst)[i] = o;
    }
}

// ---------------------------------------------------------------------------
// transpose + cast: src f32 [1024][4096] -> dst bf16 [4096][1024]
// permute=1 additionally remaps dst row n -> p*16 + g*4 + jj
//   (n = g*1024 + p*4 + jj), so each step-block's 16 B-cols = its 4 hidden
//   units x 4 gates.
// grid: (64 col-tiles, 16 row-tiles), 256 threads
// ---------------------------------------------------------------------------
__global__ __launch_bounds__(256) void transpose_cast(
    const float* __restrict__ src, ushortT* __restrict__ dst, int permute)
{
    __shared__ ushortT tile[64][66];   // 66*2B=132B rows: 33 words, gcd(33,32)=1
    const int c0 = blockIdx.x * 64, r0 = blockIdx.y * 64;
    const int cc = threadIdx.x & 63, rq = threadIdx.x >> 6;
    #pragma unroll
    for (int ps = 0; ps < 16; ++ps) {
        int r = ps * 4 + rq;
        tile[cc][r] = f2bf(src[(size_t)(r0 + r) * NG + c0 + cc]);
    }
    __syncthreads();
    #pragma unroll
    for (int ps = 0; ps < 16; ++ps) {
        int cl = ps * 4 + rq;
        int n  = c0 + cl;
        int drow = permute ? ((((n & 1023) >> 2) << 4) | ((n >> 10) << 2) | (n & 3))
                           : n;
        dst[(size_t)drow * 1024 + r0 + cc] = tile[cl][cc];
    }
}

// ---------------------------------------------------------------------------
// xW GEMM, bf16 MFMA: XW[rm, n] = sum_k xb[xrow(rm), k]*WxT[n, k] + bias[n]
// BM=BN=128, BK=32, 256 thr = 4 waves (2x2), 4x4 16x16 frags per wave.
// ---------------------------------------------------------------------------
__global__ __launch_bounds__(256) void gemm_xw_mfma(
    const ushortT* __restrict__ xb,   // [NB*NT][ND] bf16
    const ushortT* __restrict__ wxT,  // [NG][ND]    bf16
    const float* __restrict__ bias,
    float* __restrict__ XW,           // [NB*Tc][NG] f32
    int t0, int Tc, int tcsh)
{
    __shared__ ushortT As[128 * 32];  // [m][k] row-major, 64B rows
    __shared__ ushortT Bs[128 * 32];  // [n][k]

    const int tid  = threadIdx.x;
    const int lane = tid & 63;
    const int wv   = tid >> 6;
    const int wr   = wv >> 1, wc = wv & 1;
    const int n0   = blockIdx.x * 128;
    const int m0   = blockIdx.y * 128;

    // staging chunks: chunk c (0..511): row = c>>2, k-elems (c&3)*8
    // thread t owns chunks t and t+256 for both A and B.
    const int c1 = tid, c2 = tid + 256;
    const int rm1 = m0 + (c1 >> 2), rm2 = m0 + (c2 >> 2);
    const int xr1 = ((rm1 >> tcsh) * NT) + t0 + (rm1 & (Tc - 1));
    const int xr2 = ((rm2 >> tcsh) * NT) + t0 + (rm2 & (Tc - 1));
    const ushortT* ap1 = xb + (size_t)xr1 * ND + (c1 & 3) * 8;
    const ushortT* ap2 = xb + (size_t)xr2 * ND + (c2 & 3) * 8;
    const ushortT* bp1 = wxT + (size_t)(n0 + (c1 >> 2)) * ND + (c1 & 3) * 8;
    const ushortT* bp2 = wxT + (size_t)(n0 + (c2 >> 2)) * ND + (c2 & 3) * 8;

    f32x4 acc[4][4];
    #pragma unroll
    for (int m = 0; m < 4; ++m)
        #pragma unroll
        for (int n = 0; n < 4; ++n) acc[m][n] = (f32x4){0.f, 0.f, 0.f, 0.f};

    const int arow_base = (wr * 64 + (lane & 15)) * 32 + (lane >> 4) * 8;
    const int brow_base = (wc * 64 + (lane & 15)) * 32 + (lane >> 4) * 8;

    for (int k0 = 0; k0 < ND; k0 += 32) {
        short8 va1 = *(const short8*)(ap1 + k0);
        short8 va2 = *(const short8*)(ap2 + k0);
        short8 vb1 = *(const short8*)(bp1 + k0);
        short8 vb2 = *(const short8*)(bp2 + k0);
        __syncthreads();
        *(short8*)&As[c1 * 8] = va1;
        *(short8*)&As[c2 * 8] = va2;
        *(short8*)&Bs[c1 * 8] = vb1;
        *(short8*)&Bs[c2 * 8] = vb2;
        __syncthreads();
        short8 af[4], bf[4];
        #pragma unroll
        for (int m = 0; m < 4; ++m)
            af[m] = *(const short8*)&As[arow_base + m * 16 * 32];
        #pragma unroll
        for (int n = 0; n < 4; ++n)
            bf[n] = *(const short8*)&Bs[brow_base + n * 16 * 32];
        #pragma unroll
        for (int m = 0; m < 4; ++m)
            #pragma unroll
            for (int n = 0; n < 4; ++n)
                acc[m][n] = __builtin_amdgcn_mfma_f32_16x16x32_bf16(
                    af[m], bf[n], acc[m][n], 0, 0, 0);
    }

    #pragma unroll
    for (int n = 0; n < 4; ++n) {
        int col = n0 + wc * 64 + n * 16 + (lane & 15);
        float bs = bias[col];
        #pragma unroll
        for (int m = 0; m < 4; ++m) {
            #pragma unroll
            for (int r = 0; r < 4; ++r) {
                int row = m0 + wr * 64 + m * 16 + (lane >> 4) * 4 + r;
                XW[(size_t)row * NG + col] = acc[m][n][r] + bs;
            }
        }
    }
}

// ---------------------------------------------------------------------------
// One LSTM timestep, MFMA.
// Block p owns hidden cols j = p*4..p*4+3 (16 gate cols via permuted whpT).
// 4 waves: (mt = batch 16-row tile, kh = K half). 16 chained MFMAs each,
// operands straight from L2-hot global (hb 64KB, whpT shard 32KB/block).
// ---------------------------------------------------------------------------
__global__ __launch_bounds__(256) void lstm_step3(
    const float* __restrict__ XW,      // [NB*Tc][NG]
    const ushortT* __restrict__ whpT,  // [4096][1024] permuted rows
    const ushortT* __restrict__ hb,    // [32][1024] bf16
    ushortT* __restrict__ hbn,         // next h bf16
    float* __restrict__ cstate,        // [32][1024] f32 (cT slot)
    float* __restrict__ out,           // [NB][NT][NH]
    float* __restrict__ hTout,         // [32][1024]
    int t, int trel, int Tc)
{
    __shared__ float gred[2][2][16][17];

    const int tid = threadIdx.x, lane = tid & 63, wv = tid >> 6;
    const int mt = wv & 1, kh = wv >> 1;
    const int p  = blockIdx.x;

    const ushortT* arow = hb   + (size_t)(mt * 16 + (lane & 15)) * 1024
                               + kh * 512 + (lane >> 4) * 8;
    const ushortT* brow = whpT + (size_t)(p * 16 + (lane & 15)) * 1024
                               + kh * 512 + (lane >> 4) * 8;

    f32x4 acc = (f32x4){0.f, 0.f, 0.f, 0.f};
    #pragma unroll
    for (int ks = 0; ks < 16; ++ks) {
        short8 a = *(const short8*)(arow + ks * 32);
        short8 b = *(const short8*)(brow + ks * 32);
        acc = __builtin_amdgcn_mfma_f32_16x16x32_bf16(a, b, acc, 0, 0, 0);
    }
    #pragma unroll
    for (int r = 0; r < 4; ++r)
        gred[kh][mt][(lane >> 4) * 4 + r][lane & 15] = acc[r];
    __syncthreads();

    if (tid < 128) {
        const int b = tid & 31, jj = tid >> 5;
        const int mtb = b >> 4, br = b & 15;
        float g4[4];
        #pragma unroll
        for (int g = 0; g < 4; ++g) {
            int c = g * 4 + jj;
            g4[g] = gred[0][mtb][br][c] + gred[1][mtb][br][c]
                  + XW[(size_t)(b * Tc + trel) * NG + g * NH + p * 4 + jj];
        }
        float iv = 1.f / (1.f + __expf(-g4[0]));
        float fv = 1.f / (1.f + __expf(-g4[1]));
        float gv = tanhf(g4[2]);
        float ov = 1.f / (1.f + __expf(-g4[3]));

        const int j = p * 4 + jj;
        float cv = cstate[b * NH + j];
        float cn = fv * cv + iv * gv;
        float hn = ov * tanhf(cn);

        cstate[b * NH + j] = cn;
        out[((size_t)b * NT + t) * NH + j] = hn;
        hbn[b * NH + j] = f2bf(hn);
        if (t == NT - 1) hTout[b * NH + j] = hn;
    }
}

// ---------------------------------------------------------------------------
extern "C" void kernel_launch(void* const* d_in, const int* in_sizes, int n_in,
                              void* d_out, int out_size, void* d_ws, size_t ws_size,
                              hipStream_t stream) {
    const float* x    = (const float*)d_in[0];
    const float* c0   = (const float*)d_in[1];
    const float* h0   = (const float*)d_in[2];
    const float* Wx   = (const float*)d_in[3];
    const float* Wh   = (const float*)d_in[4];
    const float* bias = (const float*)d_in[5];

    float* out = (float*)d_out;
    float* cT  = out + (size_t)NB * NT * NH;   // running c state
    float* hT  = cT + (size_t)NB * NH;

    // workspace layout (bytes):
    //   xb   bf16 [NB*NT][ND]      32 MB
    //   wxT  bf16 [NG][ND]          8 MB
    //   whpT bf16 [NG][NH]          8 MB
    //   hb0, hb1 bf16 [32][1024]   64 KB each
    //   xw   f32  [NB*Tc][NG]
    ushortT* xb   = (ushortT*)d_ws;
    ushortT* wxT  = xb  + (size_t)NB * NT * ND;
    ushortT* whpT = wxT + (size_t)NG * ND;
    ushortT* hb0  = whpT + (size_t)NG * NH;
    ushortT* hb1  = hb0 + NB * NH;
    float*   xw   = (float*)(hb1 + NB * NH);

    const size_t fixed = ((size_t)NB * NT * ND + (size_t)NG * ND + (size_t)NG * NH
                          + 2 * NB * NH) * sizeof(ushortT);
    int Tc = 512;
    while (Tc > 4 && fixed + (size_t)NB * Tc * NG * sizeof(float) > ws_size)
        Tc >>= 1;
    int tcsh = 31 - __builtin_clz(Tc);

    cast_bf16<<<(NB * NT * ND / 4 + 255) / 256, 256, 0, stream>>>(x, xb, NB * NT * ND / 4);
    cast_bf16<<<(NB * NH / 4 + 255) / 256, 256, 0, stream>>>(h0, hb0, NB * NH / 4);
    transpose_cast<<<dim3(64, 16), 256, 0, stream>>>(Wx, wxT, 0);
    transpose_cast<<<dim3(64, 16), 256, 0, stream>>>(Wh, whpT, 1);
    hipMemcpyAsync(cT, c0, (size_t)NB * NH * sizeof(float),
                   hipMemcpyDeviceToDevice, stream);

    for (int t0 = 0; t0 < NT; t0 += Tc) {
        dim3 g(NG / 128, (NB * Tc) / 128);
        gemm_xw_mfma<<<g, 256, 0, stream>>>(xb, wxT, bias, xw, t0, Tc, tcsh);
        for (int t = t0; t < t0 + Tc; ++t) {
            const ushortT* hp = (t & 1) ? hb1 : hb0;
            ushortT*       hn = (t & 1) ? hb0 : hb1;
            lstm_step3<<<256, 256, 0, stream>>>(xw, whpT, hp, hn, cT, out, hT,
                                                t, t - t0, Tc);
        }
    }
}